// Round 4
// baseline (233.625 us; speedup 1.0000x reference)
//
#include <hip/hip_runtime.h>

// LIF forward: X [B, T, N] fp32 -> spikes [B, T, N] fp32
// B=128, T=32, N=8192.
//   mem = mem + (x - mem)/2 ; spike = (mem-1 > 0) ; mem = spike ? 0 : mem
// Memory-bound: 268 MB compulsory HBM traffic -> ~42 us floor at 6.4 TB/s.
// Harness dur_us includes two 512 MiB poison fills (~80 us each, ~160 us
// fixed) -> kernel portion = dur_us - ~160.
// R1: float4 naive, VGPR=24, 85.5 us (loads sunk to uses).
// R3: float2 full-occupancy TLP -> ~72 us, 2.9 TB/s.
// R5: asm 32x dwordx2 load burst + vmcnt(0) + asm stores: ~63 us. PASS.
// R6: + chunked vmcnt(28) counted waits: NEUTRAL. -> intra-wave schedule
//     irrelevant; TLP saturates.
// R7: float4 ring + prefetch + asm stores: FAIL (absmax 2.7e19).
// R8: float4, R6 structure, asm stores: FAIL (absmax ~3.2 -- stores wrote
//     membrane-valued garbage). DIAGNOSIS: VMEM store-data hazard. An asm
//     volatile store reads its data VGPRs asynchronously after issue; the
//     compiler treats the asm as complete at its program point and reuses
//     the s-quad immediately -> in-flight store reads clobbered regs.
//     SIInsertWaitcnts can't protect opaque asm. R5/R6 passed by
//     allocation luck. ASM STORES ARE STRUCTURALLY UNSOUND -- retired.
// R9 (this): keep ONLY the load-burst asm (the proven-essential part;
//     plain loads get sunk to uses by IR passes). Stores + compute are
//     plain C++ (compiler handles its own store-data hazards). Two
//     16-slot phases, each: 16x asm dwordx4 load burst -> vmcnt(0) FULL
//     drain -> re-tie -> plain compute + plain stores. Full drain before
//     compute removes every asm/compiler wait-counting interaction.
//     Width x2->x4 is the experiment: 1 KB/wave-instr matches the shape
//     of the 6.3 TB/s copy ceiling (m13) and the 6.7 TB/s fills.
//     VGPR ~90 (64 data + scan state); __launch_bounds__(256,4) caps at
//     128 -> 4 waves/SIMD -> all 4 blocks/CU resident (grid 1024).

typedef float f32x4 __attribute__((ext_vector_type(4)));

#define T_STEPS 32
#define N4 2048           // N/4 float4 elements per (b,t) row
#define TN4 (T_STEPS * N4)

__global__ __launch_bounds__(256, 4) void lif_fwd_kernel(
    const f32x4* __restrict__ X, f32x4* __restrict__ out)
{
    const int idx = blockIdx.x * blockDim.x + threadIdx.x;  // over B * N4
    const int b = idx >> 11;          // / N4
    const int n = idx & (N4 - 1);
    const size_t base = (size_t)b * (size_t)TN4 + (size_t)n;

    const f32x4* p = X + base;
    f32x4* __restrict__ po = out + base;

    float m0 = 0.f, m1 = 0.f, m2 = 0.f, m3 = 0.f;
    f32x4 x[16];

#pragma unroll
    for (int half = 0; half < 2; ++half) {
        // ---- Force-issue 16 timestep loads (volatile asm: cannot be
        // sunk or reordered; 64 data VGPRs held live). ----
#pragma unroll
        for (int t = 0; t < 16; ++t) {
            asm volatile("global_load_dwordx4 %0, %1, off"
                         : "=&v"(x[t])
                         : "v"(p));
            p += N4;
        }

        // Full drain: every x[t] is architecturally complete. No counted
        // waits -> no ledger to get wrong, no interaction with
        // compiler-inserted waits for its own stores.
        asm volatile("s_waitcnt vmcnt(0)" ::: "memory");

        // Re-tie AFTER the wait so compute cannot be hoisted above it.
#pragma unroll
        for (int t = 0; t < 16; ++t)
            asm volatile("" : "+v"(x[t]));

        // ---- Plain scan + plain stores (compiler-managed hazards). ----
#pragma unroll
        for (int t = 0; t < 16; ++t) {
            // exact reference order: mem += (x - mem) * 0.5 ; threshold 1.0
            m0 = m0 + (x[t].x - m0) * 0.5f;
            m1 = m1 + (x[t].y - m1) * 0.5f;
            m2 = m2 + (x[t].z - m2) * 0.5f;
            m3 = m3 + (x[t].w - m3) * 0.5f;

            f32x4 s;
            s.x = (m0 - 1.0f > 0.0f) ? 1.0f : 0.0f;
            s.y = (m1 - 1.0f > 0.0f) ? 1.0f : 0.0f;
            s.z = (m2 - 1.0f > 0.0f) ? 1.0f : 0.0f;
            s.w = (m3 - 1.0f > 0.0f) ? 1.0f : 0.0f;

            m0 = (s.x != 0.0f) ? 0.0f : m0;
            m1 = (s.y != 0.0f) ? 0.0f : m1;
            m2 = (s.z != 0.0f) ? 0.0f : m2;
            m3 = (s.w != 0.0f) ? 0.0f : m3;

            po[(size_t)(half * 16 + t) * (size_t)N4] = s;
        }
    }
}

extern "C" void kernel_launch(void* const* d_in, const int* in_sizes, int n_in,
                              void* d_out, int out_size, void* d_ws, size_t ws_size,
                              hipStream_t stream) {
    const f32x4* X = (const f32x4*)d_in[0];
    f32x4* out = (f32x4*)d_out;

    const int total = in_sizes[0];          // B*T*N = 33554432 elements
    const int B = total / (T_STEPS * 8192); // 128
    const int nthreads = B * N4;            // 262144

    const int block = 256;
    const int grid = (nthreads + block - 1) / block;  // 1024 = 4 blocks/CU

    lif_fwd_kernel<<<grid, block, 0, stream>>>(X, out);
}